// Round 1
// baseline (4117.741 us; speedup 1.0000x reference)
//
#include <hip/hip_runtime.h>

// ---------------- constants ----------------
namespace {
constexpr int kB      = 4096;
constexpr int kInW    = 518;     // BOUNDS + NRIM
constexpr int kNrim   = 6;
constexpr int kTop    = 4;
constexpr long long kOS = (long long)kB * 3600;   // per-output slot (B*NRIM*UNITS)

// ws offsets (in floats)
constexpr long long o_wvavg = 0;                                   // 512*400
constexpr long long o_bvavg = o_wvavg + 512LL * 400;               // 400
constexpr long long o_kh0   = o_bvavg + 400;                       // B*256
constexpr long long o_v2    = o_kh0 + (long long)kB * 256;         // B*400
constexpr long long o_qlay  = o_v2 + (long long)kB * 400;          // B*1536
constexpr long long o_mask  = o_qlay + (long long)kB * 1536;       // B*8 (6 used)
constexpr long long o_rnnin = o_mask + (long long)kB * 8;          // B*2400
constexpr long long o_ctx   = o_rnnin + (long long)kB * 2400;      // B*2400 (also gates tmp)
// reused regions
constexpr long long o_kc    = o_qlay;                              // B*768
constexpr long long o_qc    = o_qlay + (long long)kB * 768;        // B*768
constexpr long long o_vc    = o_rnnin;                             // B*2400
}

__device__ __forceinline__ float sigmoidf_(float x) { return 1.f / (1.f + __expf(-x)); }

// ---------------- generic tiled SGEMM:  C[M,N] (+)= A[M,K]*W[K,N] (+bias) ----------------
// M is always 4096 (multiple of 64); N,K arbitrary. grid = (ceil(N/64), 64), block = 256.
__global__ __launch_bounds__(256) void sgemm_kernel(
    const float* __restrict__ A, int lda,
    const float* __restrict__ W, int ldw,
    float* __restrict__ C, int ldc,
    const float* __restrict__ bias,
    int N, int Kd, int beta)
{
  __shared__ __align__(16) float As[16][68];   // [k][m], padded row to 68 (16B-aligned, conflict-free)
  __shared__ __align__(16) float Ws[16][64];   // [k][n]
  const int tid = threadIdx.x;
  const int tx = tid & 15, ty = tid >> 4;
  const int n0 = blockIdx.x * 64;
  const int m0 = blockIdx.y * 64;
  float acc[4][4] = {};

  const int a_k = tid & 15;        // k within tile
  const int a_m = tid >> 4;        // m base (+16*i)
  const int w_k = tid >> 4;        // k within tile
  const int w_n = (tid & 15) * 4;  // n within tile

  for (int k0 = 0; k0 < Kd; k0 += 16) {
#pragma unroll
    for (int i = 0; i < 4; ++i) {
      int m = m0 + a_m + 16 * i;
      int k = k0 + a_k;
      As[a_k][a_m + 16 * i] = (k < Kd) ? A[(size_t)m * lda + k] : 0.f;
    }
    {
      int k = k0 + w_k;
      float4 v = make_float4(0.f, 0.f, 0.f, 0.f);
      if (k < Kd) {
        int n = n0 + w_n;
        if (n + 3 < N) {
          v = *reinterpret_cast<const float4*>(&W[(size_t)k * ldw + n]);
        } else {
          float t0 = (n + 0 < N) ? W[(size_t)k * ldw + n + 0] : 0.f;
          float t1 = (n + 1 < N) ? W[(size_t)k * ldw + n + 1] : 0.f;
          float t2 = (n + 2 < N) ? W[(size_t)k * ldw + n + 2] : 0.f;
          float t3 = (n + 3 < N) ? W[(size_t)k * ldw + n + 3] : 0.f;
          v = make_float4(t0, t1, t2, t3);
        }
      }
      *reinterpret_cast<float4*>(&Ws[w_k][w_n]) = v;
    }
    __syncthreads();
#pragma unroll
    for (int kk = 0; kk < 16; ++kk) {
      float4 a4 = *reinterpret_cast<const float4*>(&As[kk][ty * 4]);
      float4 w4 = *reinterpret_cast<const float4*>(&Ws[kk][tx * 4]);
      float a[4] = {a4.x, a4.y, a4.z, a4.w};
      float w[4] = {w4.x, w4.y, w4.z, w4.w};
#pragma unroll
      for (int i = 0; i < 4; ++i)
#pragma unroll
        for (int j = 0; j < 4; ++j)
          acc[i][j] = fmaf(a[i], w[j], acc[i][j]);
    }
    __syncthreads();
  }

#pragma unroll
  for (int i = 0; i < 4; ++i) {
    int m = m0 + ty * 4 + i;
#pragma unroll
    for (int j = 0; j < 4; ++j) {
      int n = n0 + tx * 4 + j;
      if (n < N) {
        float v = acc[i][j];
        if (bias) v += bias[n];
        size_t off = (size_t)m * ldc + n;
        if (beta) v += C[off];
        C[off] = v;
      }
    }
  }
}

// ---------------- final GEMM: h_comm = ctx@Wout + h_new, masked select, write 2 outputs ----
// A = ctx + rim*400 (lda 2400), W = Wout_n (400x600). h_upd slot currently holds h_new.
__global__ __launch_bounds__(256) void sgemm_final_kernel(
    const float* __restrict__ A,
    const float* __restrict__ W,
    const float* __restrict__ hs,
    const float* __restrict__ mask,
    float* __restrict__ out_state,
    float* __restrict__ h_upd,
    int rim)
{
  __shared__ __align__(16) float As[16][68];
  __shared__ __align__(16) float Ws[16][64];
  const int tid = threadIdx.x;
  const int tx = tid & 15, ty = tid >> 4;
  const int n0 = blockIdx.x * 64;
  const int m0 = blockIdx.y * 64;
  float acc[4][4] = {};
  const int a_k = tid & 15;
  const int a_m = tid >> 4;
  const int w_k = tid >> 4;
  const int w_n = (tid & 15) * 4;
  const int N = 600, Kd = 400, lda = 2400, ldw = 600;

  for (int k0 = 0; k0 < Kd; k0 += 16) {
#pragma unroll
    for (int i = 0; i < 4; ++i) {
      int m = m0 + a_m + 16 * i;
      int k = k0 + a_k;
      As[a_k][a_m + 16 * i] = A[(size_t)m * lda + k];   // Kd=400 divisible by 16
    }
    {
      int k = k0 + w_k;
      int n = n0 + w_n;
      float4 v = make_float4(0.f, 0.f, 0.f, 0.f);
      if (n + 3 < N) v = *reinterpret_cast<const float4*>(&W[(size_t)k * ldw + n]);
      else {
        float t0 = (n + 0 < N) ? W[(size_t)k * ldw + n + 0] : 0.f;
        float t1 = (n + 1 < N) ? W[(size_t)k * ldw + n + 1] : 0.f;
        float t2 = (n + 2 < N) ? W[(size_t)k * ldw + n + 2] : 0.f;
        float t3 = (n + 3 < N) ? W[(size_t)k * ldw + n + 3] : 0.f;
        v = make_float4(t0, t1, t2, t3);
      }
      *reinterpret_cast<float4*>(&Ws[w_k][w_n]) = v;
    }
    __syncthreads();
#pragma unroll
    for (int kk = 0; kk < 16; ++kk) {
      float4 a4 = *reinterpret_cast<const float4*>(&As[kk][ty * 4]);
      float4 w4 = *reinterpret_cast<const float4*>(&Ws[kk][tx * 4]);
      float a[4] = {a4.x, a4.y, a4.z, a4.w};
      float w[4] = {w4.x, w4.y, w4.z, w4.w};
#pragma unroll
      for (int i = 0; i < 4; ++i)
#pragma unroll
        for (int j = 0; j < 4; ++j)
          acc[i][j] = fmaf(a[i], w[j], acc[i][j]);
    }
    __syncthreads();
  }

#pragma unroll
  for (int i = 0; i < 4; ++i) {
    int m = m0 + ty * 4 + i;
    float mk = mask[m * 6 + rim];
#pragma unroll
    for (int j = 0; j < 4; ++j) {
      int n = n0 + tx * 4 + j;
      if (n < N) {
        size_t off = (size_t)m * 3600 + rim * 600 + n;
        float v = (mk != 0.f) ? (acc[i][j] + h_upd[off]) : hs[off];
        h_upd[off] = v;        // same thread reads h_new then overwrites — safe
        out_state[off] = v;
      }
    }
  }
}

// ---------------- Wv head-average precompute ----------------
__global__ void wvavg_kernel(const float* __restrict__ Wv, const float* __restrict__ bv,
                             float* __restrict__ wvavg, float* __restrict__ bvavg)
{
  int idx = blockIdx.x * blockDim.x + threadIdx.x;
  if (idx < 512 * 400) {
    int k = idx / 400, v = idx % 400;
    const float* r = Wv + (size_t)k * 1600 + v;
    wvavg[idx] = 0.25f * (r[0] + r[400] + r[800] + r[1200]);
  }
  if (idx < 400) {
    bvavg[idx] = 0.25f * (bv[idx] + bv[idx + 400] + bv[idx + 800] + bv[idx + 1200]);
  }
}

// ---------------- scores + softmax + top-k mask + rnn_in (block per batch) ----------------
__global__ __launch_bounds__(256) void score_kernel(
    const float* __restrict__ inputs,   // B x 518 (rim_dist at 512)
    const float* __restrict__ qlay,     // B x 1536
    const float* __restrict__ kh0,      // B x 256
    const float* __restrict__ bk,       // 256
    const float* __restrict__ v2,       // B x 400
    const float* __restrict__ bvavg,    // 400 (= v2[:,1,:])
    float* __restrict__ maskout,        // B x 6
    float* __restrict__ rnnin)          // B x 2400
{
  const int b = blockIdx.x;
  const int t = threadIdx.x;
  __shared__ float red[4][12];
  __shared__ float sprob[12];
  __shared__ float smask[6];

  float k0v = kh0[(size_t)b * 256 + t];
  float bkv = bk[t];
  float part[12];
#pragma unroll
  for (int n = 0; n < 6; ++n) {
    float q = qlay[(size_t)b * 1536 + n * 256 + t];
    part[2 * n]     = q * k0v;
    part[2 * n + 1] = q * bkv;
  }
#pragma unroll
  for (int off = 32; off > 0; off >>= 1)
#pragma unroll
    for (int i = 0; i < 12; ++i)
      part[i] += __shfl_down(part[i], off);
  const int wave = t >> 6, lane = t & 63;
  if (lane == 0)
#pragma unroll
    for (int i = 0; i < 12; ++i) red[wave][i] = part[i];
  __syncthreads();
  if (t < 12) {
    float s = (red[0][t] + red[1][t] + red[2][t] + red[3][t]) * (1.0f / 32.0f);
    red[0][t] = s;
  }
  __syncthreads();
  if (t < 6) {
    float s0 = red[0][2 * t], s1 = red[0][2 * t + 1];
    float mx = fmaxf(s0, s1);
    float e0 = __expf(s0 - mx), e1 = __expf(s1 - mx);
    float inv = 1.f / (e0 + e1);
    sprob[2 * t] = e0 * inv;
    sprob[2 * t + 1] = e1 * inv;
    // top-k(4 of 6) mask with jax tie-break (earlier index wins)
    const float* rd = inputs + (size_t)b * kInW + 512;
    float mine = rd[t];
    int rank = 0;
#pragma unroll
    for (int j = 0; j < 6; ++j) {
      float o = rd[j];
      rank += (o > mine) || (o == mine && j < t);
    }
    float mk = (rank < kTop) ? 1.f : 0.f;
    smask[t] = mk;
    maskout[(size_t)b * 6 + t] = mk;
  }
  __syncthreads();
  for (int idx = t; idx < 2400; idx += 256) {
    int n = idx / 400, v = idx % 400;
    float val = (sprob[2 * n] * v2[(size_t)b * 400 + v] + sprob[2 * n + 1] * bvavg[v]) * smask[n];
    rnnin[(size_t)b * 2400 + idx] = val;
  }
}

// ---------------- LSTM pointwise (per rim) ----------------
__global__ __launch_bounds__(256) void lstm_kernel(
    const float* __restrict__ gates,  // B x 2400 for this rim
    const float* __restrict__ cs,     // B x 6 x 600
    const float* __restrict__ mask,   // B x 6
    int rim,
    float* __restrict__ c_upd,        // d_out slot 2
    float* __restrict__ h_new)        // d_out slot 1 (h_upd, temporarily h_new)
{
  int idx = blockIdx.x * blockDim.x + threadIdx.x;
  int b = idx / 600, u = idx % 600;
  const float* g = gates + (size_t)b * 2400;
  float ig = sigmoidf_(g[u]);
  float fg = sigmoidf_(g[600 + u]);
  float gg = tanhf(g[1200 + u]);
  float og = sigmoidf_(g[1800 + u]);
  size_t off = (size_t)b * 3600 + rim * 600 + u;
  float c_prev = cs[off];
  float c = fg * c_prev + ig * gg;
  float h = og * tanhf(c);
  float mk = mask[(size_t)b * 6 + rim];
  c_upd[off] = (mk != 0.f) ? c : c_prev;
  h_new[off] = h;
}

// ---------------- comm attention (block per batch): sc -> softmax -> ctx ----------------
__global__ __launch_bounds__(256) void comm_kernel(
    const float* __restrict__ kc,   // B x 768  ([m][h*32+d])
    const float* __restrict__ qc,   // B x 768
    const float* __restrict__ vc,   // B x 2400 ([m][h*100+v])
    float* __restrict__ ctx)        // B x 2400 ([n][h*100+v])
{
  const int b = blockIdx.x, t = threadIdx.x;
  __shared__ float skc[768], sqc[768], svc[2400];
  __shared__ float spc[4][6][6];
  for (int i = t; i < 768; i += 256) {
    skc[i] = kc[(size_t)b * 768 + i];
    sqc[i] = qc[(size_t)b * 768 + i];
  }
  for (int i = t; i < 2400; i += 256) svc[i] = vc[(size_t)b * 2400 + i];
  __syncthreads();
  if (t < 144) {
    int h = t / 36, n = (t % 36) / 6, m = t % 6;
    float s = 0.f;
#pragma unroll
    for (int d = 0; d < 32; ++d) s += sqc[n * 128 + h * 32 + d] * skc[m * 128 + h * 32 + d];
    spc[h][n][m] = s * 0.17677669529663687f;   // 1/sqrt(32)
  }
  __syncthreads();
  if (t < 24) {
    int h = t / 6, n = t % 6;
    float mx = -3.0e38f;
#pragma unroll
    for (int m = 0; m < 6; ++m) mx = fmaxf(mx, spc[h][n][m]);
    float e[6], sum = 0.f;
#pragma unroll
    for (int m = 0; m < 6; ++m) { e[m] = __expf(spc[h][n][m] - mx); sum += e[m]; }
    float inv = 1.f / sum;
#pragma unroll
    for (int m = 0; m < 6; ++m) spc[h][n][m] = e[m] * inv;
  }
  __syncthreads();
  for (int idx = t; idx < 2400; idx += 256) {
    int n = idx / 400, r = idx % 400, h = r / 100, v = r % 100;
    float s = 0.f;
#pragma unroll
    for (int m = 0; m < 6; ++m) s += spc[h][n][m] * svc[m * 400 + h * 100 + v];
    ctx[(size_t)b * 2400 + idx] = s;
  }
}

// ---------------- launch ----------------
extern "C" void kernel_launch(void* const* d_in, const int* in_sizes, int n_in,
                              void* d_out, int out_size, void* d_ws, size_t ws_size,
                              hipStream_t stream) {
  const float* inputs = (const float*)d_in[0];
  const float* hs     = (const float*)d_in[1];
  const float* cs     = (const float*)d_in[2];
  const float* Wk     = (const float*)d_in[3];
  const float* bk     = (const float*)d_in[4];
  const float* Wv     = (const float*)d_in[5];
  const float* bv     = (const float*)d_in[6];
  const float* Wq     = (const float*)d_in[7];
  const float* lstm_k = (const float*)d_in[8];
  const float* lstm_r = (const float*)d_in[9];
  const float* lstm_b = (const float*)d_in[10];
  const float* Wkc    = (const float*)d_in[11];
  const float* Wvc    = (const float*)d_in[12];
  const float* Wqc    = (const float*)d_in[13];
  const float* Wout   = (const float*)d_in[14];
  float* out = (float*)d_out;
  float* ws  = (float*)d_ws;

  float* out_state = out;
  float* h_upd = out + kOS;     // holds h_new until final kernels
  float* c_upd = out + 2 * kOS;

  dim3 blk(256);

  // 1) Wv head-average
  wvavg_kernel<<<dim3(800), blk, 0, stream>>>(Wv, bv, ws + o_wvavg, ws + o_bvavg);
  // 2) kh0 = x @ Wk + bk
  sgemm_kernel<<<dim3(4, 64), blk, 0, stream>>>(inputs, kInW, Wk, 256, ws + o_kh0, 256, bk, 256, 512, 0);
  // 3) v2_0 = x @ Wv_avg + bv_avg
  sgemm_kernel<<<dim3(7, 64), blk, 0, stream>>>(inputs, kInW, ws + o_wvavg, 400, ws + o_v2, 400,
                                                ws + o_bvavg, 400, 512, 0);
  // 4) q_lay[:,n,:] = hs[:,n,:] @ Wq[n]
  for (int n = 0; n < kNrim; ++n)
    sgemm_kernel<<<dim3(4, 64), blk, 0, stream>>>(hs + n * 600, 3600, Wq + (size_t)n * 600 * 256, 256,
                                                  ws + o_qlay + n * 256, 1536, nullptr, 256, 600, 0);
  // 5) scores, softmax, top-k mask, rnn_in
  score_kernel<<<dim3(kB), blk, 0, stream>>>(inputs, ws + o_qlay, ws + o_kh0, bk, ws + o_v2,
                                             ws + o_bvavg, ws + o_mask, ws + o_rnnin);
  // 6) gates GEMMs + LSTM pointwise, per rim (gates tmp in o_ctx region)
  for (int n = 0; n < kNrim; ++n) {
    sgemm_kernel<<<dim3(38, 64), blk, 0, stream>>>(ws + o_rnnin + n * 400, 2400,
                                                   lstm_k + (size_t)n * 400 * 2400, 2400,
                                                   ws + o_ctx, 2400, lstm_b + n * 2400, 2400, 400, 0);
    sgemm_kernel<<<dim3(38, 64), blk, 0, stream>>>(hs + n * 600, 3600,
                                                   lstm_r + (size_t)n * 600 * 2400, 2400,
                                                   ws + o_ctx, 2400, nullptr, 2400, 600, 1);
    lstm_kernel<<<dim3((kB * 600) / 256), blk, 0, stream>>>(ws + o_ctx, cs, ws + o_mask, n, c_upd, h_upd);
  }
  // 7) kc, qc, vc from h_new
  for (int n = 0; n < kNrim; ++n) {
    sgemm_kernel<<<dim3(2, 64), blk, 0, stream>>>(h_upd + n * 600, 3600, Wkc + (size_t)n * 600 * 128, 128,
                                                  ws + o_kc + n * 128, 768, nullptr, 128, 600, 0);
    sgemm_kernel<<<dim3(2, 64), blk, 0, stream>>>(h_upd + n * 600, 3600, Wqc + (size_t)n * 600 * 128, 128,
                                                  ws + o_qc + n * 128, 768, nullptr, 128, 600, 0);
    sgemm_kernel<<<dim3(7, 64), blk, 0, stream>>>(h_upd + n * 600, 3600, Wvc + (size_t)n * 600 * 400, 400,
                                                  ws + o_vc + n * 400, 2400, nullptr, 400, 600, 0);
  }
  // 8) comm attention -> ctx
  comm_kernel<<<dim3(kB), blk, 0, stream>>>(ws + o_kc, ws + o_qc, ws + o_vc, ws + o_ctx);
  // 9) h_comm = ctx @ Wout + h_new; masked select; write out_state + h_upd
  for (int n = 0; n < kNrim; ++n)
    sgemm_final_kernel<<<dim3(10, 64), blk, 0, stream>>>(ws + o_ctx + n * 400,
                                                         Wout + (size_t)n * 400 * 600,
                                                         hs, ws + o_mask, out_state, h_upd, n);
}

// Round 2
// 807.671 us; speedup vs baseline: 5.0983x; 5.0983x over previous
//
#include <hip/hip_runtime.h>

namespace {
typedef unsigned short u16;
typedef __attribute__((ext_vector_type(8))) __bf16 bf16x8;
typedef __attribute__((ext_vector_type(4))) float f32x4;

constexpr long long kB  = 4096;
constexpr long long kOS = kB * 3600;

// ---- ws byte offsets ----
constexpr size_t oWkT   = 0;
constexpr size_t oWvavT = oWkT   + 256ull*512*2;
constexpr size_t oWqT   = oWvavT + 448ull*512*2;
constexpr size_t oWkcT  = oWqT   + 6ull*256*608*2;
constexpr size_t oWqcT  = oWkcT  + 6ull*128*608*2;
constexpr size_t oWvcT  = oWqcT  + 6ull*128*608*2;
constexpr size_t oWoutT = oWvcT  + 6ull*448*608*2;
constexpr size_t oLstmT = oWoutT + 6ull*640*416*2;
constexpr size_t oBp    = oLstmT + 6ull*2432*1024*2;
constexpr size_t oBvavg = oBp    + 6ull*2432*4;
constexpr size_t oZero  = oBvavg + 512*4;
constexpr size_t oMask  = oZero  + 256;
constexpr size_t oArena = oMask  + 4096ull*6*4;
// phase-1 arena
constexpr size_t oHs2   = oArena;                          // bf16 hs [4096][3600]+64
constexpr size_t oRnn   = oHs2  + (4096ull*3600+64)*2;     // bf16 rnn_in [4096][2400]
constexpr size_t oXbf   = oRnn  + 4096ull*2400*2;          // bf16 x [4096][512]
constexpr size_t oKh0   = oXbf  + 4096ull*512*2;           // bf16 kh0 [4096][256]
constexpr size_t oV2    = oKh0  + 4096ull*256*2;           // bf16 v2 [4096][400]
constexpr size_t oQlay  = oV2   + 4096ull*400*2;           // bf16 qlay [4096][1536]
// phase-2 overlay (same arena; earlier buffers dead by then)
constexpr size_t oVc    = oArena;                          // bf16 vc [4096][2400]
constexpr size_t oCtx   = oVc   + 4096ull*2400*2;          // bf16 ctx [4096][2400]+64
constexpr size_t oKc    = oCtx  + (4096ull*2400+64)*2;     // bf16 kc [4096][768]
constexpr size_t oQc    = oKc   + 4096ull*768*2;           // bf16 qc [4096][768]
}

__device__ __forceinline__ u16 f2b(float f) {
  union { float f; unsigned u; } x; x.f = f;
  unsigned r = (x.u + 0x7fffu + ((x.u >> 16) & 1u)) >> 16;
  return (u16)r;
}
__device__ __forceinline__ float b2f(u16 u) {
  union { unsigned u; float f; } x; x.u = ((unsigned)u) << 16;
  return x.f;
}
__device__ __forceinline__ float sigmoidf_(float x) { return 1.f / (1.f + __expf(-x)); }

__device__ __forceinline__ void gload16(const void* g, void* l) {
  __builtin_amdgcn_global_load_lds((const __attribute__((address_space(1))) void*)g,
                                   (__attribute__((address_space(3))) void*)l, 16, 0, 0);
}

union FragU { uint2 u2[2]; bf16x8 v; };

// ================= generic bf16 MFMA GEMM =================
// BM=128, BN=64, BK=32. 256 threads = 4 waves, each 32(M)x64(N).
// A: bf16 [4096][lda] (+per-rim offset strideA). Bt: bf16 [Npad][Kpad] (n-major).
// MODE 0: C = A*B (+bias), store f32 or bf16.
// MODE 1: final: v = mask ? acc + h_upd : hs ; write h_upd & out_state.
// MODE 2: gates (dual-source A: k<400 rnn_in, 400..999 hs2, else zero) + fused LSTM.
template<int MODE>
__global__ __launch_bounds__(256) void gemm16(
    const u16* __restrict__ A, int lda, int strideA,
    const u16* __restrict__ A2, int lda2, int strideA2,
    const u16* __restrict__ Bt, int strideB, int Kpad,
    void* __restrict__ C, int ldc, int strideC,
    const float* __restrict__ bias, int strideBias,
    int N, int nks, int storeBf16,
    const u16* __restrict__ zerobuf,
    const float* __restrict__ cs, const float* __restrict__ mask,
    float* __restrict__ c_upd, float* __restrict__ h_upd, u16* __restrict__ hnbf,
    const float* __restrict__ hs_in, float* __restrict__ out_state)
{
  __shared__ __align__(16) u16 As[128 * 32];
  __shared__ __align__(16) u16 Bs[64 * 32];
  const int rim = blockIdx.z;
  const int m0 = blockIdx.y * 128;
  const int n0 = blockIdx.x * 64;
  A += (size_t)rim * strideA;
  if (A2) A2 += (size_t)rim * strideA2;
  Bt += (size_t)rim * strideB;
  if (bias) bias += (size_t)rim * strideBias;

  const int t = threadIdx.x;
  const int w = t >> 6, lane = t & 63;
  const int lrow = lane & 15, lk = lane >> 4;

  f32x4 acc[2][4] = {};

  const int rowA0 = t >> 2;
  const int rowA1 = (t + 256) >> 2;
  const int csA0 = (t & 3) ^ ((rowA0 >> 1) & 3);
  const int csA1 = (t & 3) ^ ((rowA1 >> 1) & 3);
  const int rowB = t >> 2;
  const int csB  = (t & 3) ^ ((rowB >> 1) & 3);

  for (int s = 0; s < nks; ++s) {
    const int k0 = s * 32;
    {
      const int gk0 = k0 + csA0 * 8, gk1 = k0 + csA1 * 8;
      const u16 *p0, *p1;
      if (MODE == 2) {
        p0 = (gk0 < 400)  ? A  + (size_t)(m0 + rowA0) * lda  + gk0
           : (gk0 < 1000) ? A2 + (size_t)(m0 + rowA0) * lda2 + (gk0 - 400)
                          : zerobuf;
        p1 = (gk1 < 400)  ? A  + (size_t)(m0 + rowA1) * lda  + gk1
           : (gk1 < 1000) ? A2 + (size_t)(m0 + rowA1) * lda2 + (gk1 - 400)
                          : zerobuf;
      } else {
        p0 = A + (size_t)(m0 + rowA0) * lda + gk0;
        p1 = A + (size_t)(m0 + rowA1) * lda + gk1;
      }
      gload16(p0, &As[(size_t)t * 8]);
      gload16(p1, &As[(size_t)(t + 256) * 8]);
      const u16* pb = Bt + (size_t)(n0 + rowB) * Kpad + k0 + csB * 8;
      gload16(pb, &Bs[(size_t)t * 8]);
    }
    __syncthreads();
    FragU af[2], bfr[4];
#pragma unroll
    for (int mf = 0; mf < 2; ++mf) {
      const int r = w * 32 + mf * 16 + lrow;
      const int sw = ((r >> 1) & 3) << 4;
      const char* base = (const char*)As + r * 64;
      af[mf].u2[0] = *(const uint2*)(base + ((8 * lk) ^ sw));
      af[mf].u2[1] = *(const uint2*)(base + ((8 * lk + 32) ^ sw));
    }
#pragma unroll
    for (int nf = 0; nf < 4; ++nf) {
      const int r = nf * 16 + lrow;
      const int sw = ((r >> 1) & 3) << 4;
      const char* base = (const char*)Bs + r * 64;
      bfr[nf].u2[0] = *(const uint2*)(base + ((8 * lk) ^ sw));
      bfr[nf].u2[1] = *(const uint2*)(base + ((8 * lk + 32) ^ sw));
    }
#pragma unroll
    for (int mf = 0; mf < 2; ++mf)
#pragma unroll
      for (int nf = 0; nf < 4; ++nf)
        acc[mf][nf] = __builtin_amdgcn_mfma_f32_16x16x32_bf16(af[mf].v, bfr[nf].v, acc[mf][nf], 0, 0, 0);
    __syncthreads();
  }

  if (MODE == 0) {
    float* Cf = (float*)C + (size_t)rim * strideC;
    u16*   Cu = (u16*)C + (size_t)rim * strideC;
#pragma unroll
    for (int mf = 0; mf < 2; ++mf)
#pragma unroll
      for (int r2 = 0; r2 < 4; ++r2) {
        const int m = m0 + w * 32 + mf * 16 + 4 * lk + r2;
#pragma unroll
        for (int nf = 0; nf < 4; ++nf) {
          const int col = n0 + nf * 16 + lrow;
          if (col < N) {
            float v = acc[mf][nf][r2];
            if (bias) v += bias[col];
            const size_t off = (size_t)m * ldc + col;
            if (storeBf16) Cu[off] = f2b(v); else Cf[off] = v;
          }
        }
      }
  } else if (MODE == 1) {
#pragma unroll
    for (int mf = 0; mf < 2; ++mf)
#pragma unroll
      for (int r2 = 0; r2 < 4; ++r2) {
        const int m = m0 + w * 32 + mf * 16 + 4 * lk + r2;
        const float mk = mask[(size_t)m * 6 + rim];
#pragma unroll
        for (int nf = 0; nf < 4; ++nf) {
          const int col = n0 + nf * 16 + lrow;
          if (col < N) {
            const size_t off = (size_t)m * 3600 + rim * 600 + col;
            const float v = (mk != 0.f) ? (acc[mf][nf][r2] + h_upd[off]) : hs_in[off];
            h_upd[off] = v;
            out_state[off] = v;
          }
        }
      }
  } else {  // MODE 2: gates + LSTM fused. cols n0..n0+63 = unit group (n0>>6)*16, gates 0..3 by 16s
    const int u = ((n0 >> 6) << 4) + lrow;
    if (u < 600) {
      const float bi = bias[n0 + lrow];
      const float bff = bias[n0 + 16 + lrow];
      const float bg = bias[n0 + 32 + lrow];
      const float bo = bias[n0 + 48 + lrow];
#pragma unroll
      for (int mf = 0; mf < 2; ++mf)
#pragma unroll
        for (int r2 = 0; r2 < 4; ++r2) {
          const int m = m0 + w * 32 + mf * 16 + 4 * lk + r2;
          const float iv = acc[mf][0][r2] + bi;
          const float fv = acc[mf][1][r2] + bff;
          const float gv = acc[mf][2][r2] + bg;
          const float ov = acc[mf][3][r2] + bo;
          const size_t off = (size_t)m * 3600 + rim * 600 + u;
          const float cprev = cs[off];
          const float cv = sigmoidf_(fv) * cprev + sigmoidf_(iv) * tanhf(gv);
          const float hv = sigmoidf_(ov) * tanhf(cv);
          const float mk = mask[(size_t)m * 6 + rim];
          c_upd[off] = (mk != 0.f) ? cv : cprev;
          h_upd[off] = hv;
          hnbf[off]  = f2b(hv);
        }
    }
  }
}

// ================= weight pack: out[n][k] bf16 = in[k][colmap(n)] =================
__global__ __launch_bounds__(256) void pack_wt(
    const float* __restrict__ in1, long s1,
    const float* __restrict__ in2, long s2,
    int K1, int Ktot, int ldin, int Nreal,
    u16* __restrict__ out, long so, int Kpad, int gateperm)
{
  __shared__ float tile[64][65];
  const int rim = blockIdx.z;
  const float* i1 = in1 + (size_t)rim * s1;
  const float* i2 = in2 ? in2 + (size_t)rim * s2 : nullptr;
  u16* o = out + (size_t)rim * so;
  const int n0 = blockIdx.x * 64, k0 = blockIdx.y * 64;
  const int lane = threadIdx.x & 63, q = threadIdx.x >> 6;
  const int n = n0 + lane;
  int col;
  if (gateperm) {
    const int g = (n >> 4) & 3, u = ((n >> 6) << 4) + (n & 15);
    col = (u < 600) ? g * 600 + u : -1;
  } else {
    col = (n < Nreal) ? n : -1;
  }
#pragma unroll
  for (int i = 0; i < 16; ++i) {
    const int kk = q + 4 * i;
    const int k = k0 + kk;
    float v = 0.f;
    if (col >= 0) {
      if (k < K1) v = i1[(size_t)k * ldin + col];
      else if (k < Ktot) v = i2[(size_t)(k - K1) * ldin + col];
    }
    tile[kk][lane] = v;
  }
  __syncthreads();
#pragma unroll
  for (int i = 0; i < 16; ++i) {
    const int nn = q + 4 * i;
    const int k = k0 + lane;
    if (k < Kpad) o[(size_t)(n0 + nn) * Kpad + k] = f2b(tile[lane][nn]);
  }
}

__global__ void pack_wvavg(const float* __restrict__ Wv, u16* __restrict__ out) {
  const int idx = blockIdx.x * 256 + threadIdx.x;
  if (idx >= 448 * 512) return;
  const int k = idx / 448, n = idx % 448;
  float v = 0.f;
  if (n < 400) {
    const float* r = Wv + (size_t)k * 1600 + n;
    v = 0.25f * (r[0] + r[400] + r[800] + r[1200]);
  }
  out[(size_t)n * 512 + k] = f2b(v);
}

__global__ void pack_misc(const float* __restrict__ lstm_b, const float* __restrict__ bv,
                          float* __restrict__ bp, float* __restrict__ bvavg, u16* __restrict__ zerobuf) {
  const int t = blockIdx.x * 256 + threadIdx.x;
  if (t < 6 * 2432) {
    const int rim = t / 2432, p = t % 2432;
    const int g = (p >> 4) & 3, u = ((p >> 6) << 4) + (p & 15);
    bp[t] = (u < 600) ? lstm_b[(size_t)rim * 2400 + g * 600 + u] : 0.f;
  }
  if (t < 512) bvavg[t] = (t < 400) ? 0.25f * (bv[t] + bv[t + 400] + bv[t + 800] + bv[t + 1200]) : 0.f;
  if (t < 128) zerobuf[t] = 0;
}

__global__ void pack_x(const float* __restrict__ inputs, u16* __restrict__ xbf) {
  const int idx = blockIdx.x * 256 + threadIdx.x;
  if (idx < 4096 * 512) {
    const int b = idx >> 9, c = idx & 511;
    xbf[idx] = f2b(inputs[(size_t)b * 518 + c]);
  }
}

__global__ void pack_hs2(const float* __restrict__ hs, u16* __restrict__ out) {
  const long long idx = (long long)blockIdx.x * 256 + threadIdx.x;
  const long long total = 4096ll * 3600 + 64;
  if (idx < total) out[idx] = f2b(idx < 4096ll * 3600 ? hs[idx] : 0.f);
}

// ============ scores + softmax + top-k mask + rnn_in ============
__global__ __launch_bounds__(256) void score_kernel(
    const float* __restrict__ inputs, const u16* __restrict__ qlayb,
    const u16* __restrict__ kh0b, const float* __restrict__ bk,
    const u16* __restrict__ v2b, const float* __restrict__ bvavg,
    float* __restrict__ maskout, u16* __restrict__ rnnin)
{
  const int b = blockIdx.x;
  const int t = threadIdx.x;
  __shared__ float red[4][12];
  __shared__ float sprob[12];
  __shared__ float smask[6];

  const float k0v = b2f(kh0b[(size_t)b * 256 + t]);
  const float bkv = bk[t];
  float part[12];
#pragma unroll
  for (int n = 0; n < 6; ++n) {
    const float q = b2f(qlayb[(size_t)b * 1536 + n * 256 + t]);
    part[2 * n]     = q * k0v;
    part[2 * n + 1] = q * bkv;
  }
#pragma unroll
  for (int off = 32; off > 0; off >>= 1)
#pragma unroll
    for (int i = 0; i < 12; ++i)
      part[i] += __shfl_down(part[i], off);
  const int wave = t >> 6, lane = t & 63;
  if (lane == 0)
#pragma unroll
    for (int i = 0; i < 12; ++i) red[wave][i] = part[i];
  __syncthreads();
  if (t < 12) red[0][t] = (red[0][t] + red[1][t] + red[2][t] + red[3][t]) * (1.0f / 32.0f);
  __syncthreads();
  if (t < 6) {
    const float s0 = red[0][2 * t], s1 = red[0][2 * t + 1];
    const float mx = fmaxf(s0, s1);
    const float e0 = __expf(s0 - mx), e1 = __expf(s1 - mx);
    const float inv = 1.f / (e0 + e1);
    sprob[2 * t] = e0 * inv;
    sprob[2 * t + 1] = e1 * inv;
    const float* rd = inputs + (size_t)b * 518 + 512;
    const float mine = rd[t];
    int rank = 0;
#pragma unroll
    for (int j = 0; j < 6; ++j) {
      const float o = rd[j];
      rank += (o > mine) || (o == mine && j < t);
    }
    const float mk = (rank < 4) ? 1.f : 0.f;
    smask[t] = mk;
    maskout[(size_t)b * 6 + t] = mk;
  }
  __syncthreads();
  for (int idx = t; idx < 2400; idx += 256) {
    const int n = idx / 400, v = idx % 400;
    const float val = (sprob[2 * n] * b2f(v2b[(size_t)b * 400 + v]) + sprob[2 * n + 1] * bvavg[v]) * smask[n];
    rnnin[(size_t)b * 2400 + idx] = f2b(val);
  }
}

// ============ comm attention ============
__global__ __launch_bounds__(256) void comm_kernel(
    const u16* __restrict__ kc, const u16* __restrict__ qc,
    const u16* __restrict__ vc, u16* __restrict__ ctx)
{
  const int b = blockIdx.x, t = threadIdx.x;
  __shared__ float skc[768], sqc[768], svc[2400];
  __shared__ float spc[4][6][6];
  for (int i = t; i < 768; i += 256) {
    skc[i] = b2f(kc[(size_t)b * 768 + i]);
    sqc[i] = b2f(qc[(size_t)b * 768 + i]);
  }
  for (int i = t; i < 2400; i += 256) svc[i] = b2f(vc[(size_t)b * 2400 + i]);
  __syncthreads();
  if (t < 144) {
    const int h = t / 36, n = (t % 36) / 6, m = t % 6;
    float s = 0.f;
#pragma unroll
    for (int d = 0; d < 32; ++d) s += sqc[n * 128 + h * 32 + d] * skc[m * 128 + h * 32 + d];
    spc[h][n][m] = s * 0.17677669529663687f;
  }
  __syncthreads();
  if (t < 24) {
    const int h = t / 6, n = t % 6;
    float mx = -3.0e38f;
#pragma unroll
    for (int m = 0; m < 6; ++m) mx = fmaxf(mx, spc[h][n][m]);
    float e[6], sum = 0.f;
#pragma unroll
    for (int m = 0; m < 6; ++m) { e[m] = __expf(spc[h][n][m] - mx); sum += e[m]; }
    const float inv = 1.f / sum;
#pragma unroll
    for (int m = 0; m < 6; ++m) spc[h][n][m] = e[m] * inv;
  }
  __syncthreads();
  for (int idx = t; idx < 2400; idx += 256) {
    const int n = idx / 400, r = idx % 400, h = r / 100, v = r % 100;
    float s = 0.f;
#pragma unroll
    for (int m = 0; m < 6; ++m) s += spc[h][n][m] * svc[m * 400 + h * 100 + v];
    ctx[(size_t)b * 2400 + idx] = f2b(s);
  }
}

// ================= launch =================
extern "C" void kernel_launch(void* const* d_in, const int* in_sizes, int n_in,
                              void* d_out, int out_size, void* d_ws, size_t ws_size,
                              hipStream_t stream) {
  const float* inputs = (const float*)d_in[0];
  const float* hs     = (const float*)d_in[1];
  const float* cs     = (const float*)d_in[2];
  const float* Wk     = (const float*)d_in[3];
  const float* bk     = (const float*)d_in[4];
  const float* Wv     = (const float*)d_in[5];
  const float* lstm_k = (const float*)d_in[8];
  const float* lstm_r = (const float*)d_in[9];
  const float* lstm_b = (const float*)d_in[10];
  const float* Wkc    = (const float*)d_in[11];
  const float* Wvc    = (const float*)d_in[12];
  const float* Wqc    = (const float*)d_in[13];
  const float* Wout   = (const float*)d_in[14];
  const float* Wq     = (const float*)d_in[7];
  const float* bv     = (const float*)d_in[6];

  float* out = (float*)d_out;
  float* out_state = out;
  float* h_upd = out + kOS;
  float* c_upd = out + 2 * kOS;
  u16*   hnbf  = (u16*)d_out;     // scratch alias in out_state slot (dead until final GEMM)

  char* wsb = (char*)d_ws;
  u16* WkT   = (u16*)(wsb + oWkT);
  u16* WvavT = (u16*)(wsb + oWvavT);
  u16* WqT   = (u16*)(wsb + oWqT);
  u16* WkcT  = (u16*)(wsb + oWkcT);
  u16* WqcT  = (u16*)(wsb + oWqcT);
  u16* WvcT  = (u16*)(wsb + oWvcT);
  u16* WoutT = (u16*)(wsb + oWoutT);
  u16* LstmT = (u16*)(wsb + oLstmT);
  float* bp    = (float*)(wsb + oBp);
  float* bvavg = (float*)(wsb + oBvavg);
  u16*   zerob = (u16*)(wsb + oZero);
  float* maskf = (float*)(wsb + oMask);
  u16* hs2   = (u16*)(wsb + oHs2);
  u16* rnn   = (u16*)(wsb + oRnn);
  u16* xbf   = (u16*)(wsb + oXbf);
  u16* kh0b  = (u16*)(wsb + oKh0);
  u16* v2b   = (u16*)(wsb + oV2);
  u16* qlayb = (u16*)(wsb + oQlay);
  u16* vcb   = (u16*)(wsb + oVc);
  u16* ctxb  = (u16*)(wsb + oCtx);
  u16* kcb   = (u16*)(wsb + oKc);
  u16* qcb   = (u16*)(wsb + oQc);

  dim3 B256(256);

  // ---- packs ----
  pack_misc<<<57, B256, 0, stream>>>(lstm_b, bv, bp, bvavg, zerob);
  pack_wvavg<<<896, B256, 0, stream>>>(Wv, WvavT);
  pack_wt<<<dim3(4, 8, 1),  B256, 0, stream>>>(Wk, 0, nullptr, 0, 512, 512, 256, 256, WkT, 0, 512, 0);
  pack_wt<<<dim3(4, 10, 6), B256, 0, stream>>>(Wq, 600ll*256, nullptr, 0, 600, 600, 256, 256, WqT, 256ll*608, 608, 0);
  pack_wt<<<dim3(2, 10, 6), B256, 0, stream>>>(Wkc, 600ll*128, nullptr, 0, 600, 600, 128, 128, WkcT, 128ll*608, 608, 0);
  pack_wt<<<dim3(2, 10, 6), B256, 0, stream>>>(Wqc, 600ll*128, nullptr, 0, 600, 600, 128, 128, WqcT, 128ll*608, 608, 0);
  pack_wt<<<dim3(7, 10, 6), B256, 0, stream>>>(Wvc, 600ll*400, nullptr, 0, 600, 600, 400, 400, WvcT, 448ll*608, 608, 0);
  pack_wt<<<dim3(10, 7, 6), B256, 0, stream>>>(Wout, 400ll*600, nullptr, 0, 400, 400, 600, 600, WoutT, 640ll*416, 416, 0);
  pack_wt<<<dim3(38, 16, 6), B256, 0, stream>>>(lstm_k, 400ll*2400, lstm_r, 600ll*2400, 400, 1000, 2400, 2400, LstmT, 2432ll*1024, 1024, 1);
  pack_x<<<8192, B256, 0, stream>>>(inputs, xbf);
  pack_hs2<<<57601, B256, 0, stream>>>(hs, hs2);

  // ---- phase 1 GEMMs ----
  gemm16<0><<<dim3(4, 32, 1), B256, 0, stream>>>(xbf, 512, 0, nullptr, 0, 0, WkT, 0, 512,
      kh0b, 256, 0, bk, 0, 256, 16, 1, zerob, nullptr, nullptr, nullptr, nullptr, nullptr, nullptr, nullptr);
  gemm16<0><<<dim3(7, 32, 1), B256, 0, stream>>>(xbf, 512, 0, nullptr, 0, 0, WvavT, 0, 512,
      v2b, 400, 0, bvavg, 0, 400, 16, 1, zerob, nullptr, nullptr, nullptr, nullptr, nullptr, nullptr, nullptr);
  gemm16<0><<<dim3(4, 32, 6), B256, 0, stream>>>(hs2, 3600, 600, nullptr, 0, 0, WqT, 256*608, 608,
      qlayb, 1536, 256, nullptr, 0, 256, 19, 1, zerob, nullptr, nullptr, nullptr, nullptr, nullptr, nullptr, nullptr);

  score_kernel<<<4096, B256, 0, stream>>>(inputs, qlayb, kh0b, bk, v2b, bvavg, maskf, rnn);

  // ---- gates + fused LSTM ----
  gemm16<2><<<dim3(38, 32, 6), B256, 0, stream>>>(rnn, 2400, 400, hs2, 3600, 600, LstmT, 2432*1024, 1024,
      nullptr, 0, 0, bp, 2432, 2432, 32, 0, zerob, cs, maskf, c_upd, h_upd, hnbf, nullptr, nullptr);

  // ---- comm projections ----
  gemm16<0><<<dim3(2, 32, 6), B256, 0, stream>>>(hnbf, 3600, 600, nullptr, 0, 0, WkcT, 128*608, 608,
      kcb, 768, 128, nullptr, 0, 128, 19, 1, zerob, nullptr, nullptr, nullptr, nullptr, nullptr, nullptr, nullptr);
  gemm16<0><<<dim3(2, 32, 6), B256, 0, stream>>>(hnbf, 3600, 600, nullptr, 0, 0, WqcT, 128*608, 608,
      qcb, 768, 128, nullptr, 0, 128, 19, 1, zerob, nullptr, nullptr, nullptr, nullptr, nullptr, nullptr, nullptr);
  gemm16<0><<<dim3(7, 32, 6), B256, 0, stream>>>(hnbf, 3600, 600, nullptr, 0, 0, WvcT, 448*608, 608,
      vcb, 2400, 400, nullptr, 0, 400, 19, 1, zerob, nullptr, nullptr, nullptr, nullptr, nullptr, nullptr, nullptr);

  comm_kernel<<<4096, B256, 0, stream>>>(kcb, qcb, vcb, ctxb);

  // ---- final: h_comm + select, write out_state / h_upd ----
  gemm16<1><<<dim3(10, 32, 6), B256, 0, stream>>>(ctxb, 2400, 400, nullptr, 0, 0, WoutT, 640*416, 416,
      nullptr, 0, 0, nullptr, 0, 600, 13, 0, zerob, nullptr, maskf, nullptr, h_upd, nullptr, hs, out_state);
}

// Round 3
// 680.071 us; speedup vs baseline: 6.0549x; 1.1876x over previous
//
#include <hip/hip_runtime.h>

namespace {
typedef unsigned short u16;
typedef __attribute__((ext_vector_type(8))) __bf16 bf16x8;
typedef __attribute__((ext_vector_type(4))) float f32x4;

constexpr long long kB  = 4096;
constexpr long long kOS = kB * 3600;

// ---- ws byte offsets ----
constexpr size_t oWkvT  = 0;                               // bf16 [768][512]
constexpr size_t oWqT   = oWkvT  + 768ull*512*2;           // bf16 [6][256][608]
constexpr size_t oWcomT = oWqT   + 6ull*256*608*2;         // bf16 [6][768][608]
constexpr size_t oWoutT = oWcomT + 6ull*768*608*2;         // bf16 [6][640][416]
constexpr size_t oLstmT = oWoutT + 6ull*640*416*2;         // bf16 [6][2432][1024]
constexpr size_t oBp    = oLstmT + 6ull*2432*1024*2;       // f32 [6][2432]
constexpr size_t oBkv   = oBp    + 6ull*2432*4;            // f32 [768]
constexpr size_t oZero  = oBkv   + 768*4;                  // 256 B
constexpr size_t oMask  = oZero  + 256;                    // f32 [4096][6]
constexpr size_t oArena = oMask  + 4096ull*6*4;
// phase-1 arena
constexpr size_t oHs2   = oArena;                          // bf16 [4096][3600]+64
constexpr size_t oRnn   = oHs2  + (4096ull*3600+64)*2;     // bf16 [4096][2400]
constexpr size_t oKV    = oRnn  + 4096ull*2400*2;          // bf16 [4096][768]
constexpr size_t oXbf   = oKV   + 4096ull*768*2;           // bf16 [4096][512]
constexpr size_t oQlay  = oXbf;                            // bf16 [4096][1536], overlays xbf AFTER kv gemm
// phase-2 overlay (phase-1 arena dead by then)
constexpr size_t oCqv   = oArena;                          // bf16 [4096][4608]  (kc|qc|vc per rim, 768 each)
constexpr size_t oCtx   = oCqv  + 4096ull*4608*2;          // bf16 [4096][2400]+64
}

__device__ __forceinline__ u16 f2b(float f) {
  union { float f; unsigned u; } x; x.f = f;
  unsigned r = (x.u + 0x7fffu + ((x.u >> 16) & 1u)) >> 16;
  return (u16)r;
}
__device__ __forceinline__ float b2f(u16 u) {
  union { unsigned u; float f; } x; x.u = ((unsigned)u) << 16;
  return x.f;
}
__device__ __forceinline__ float sigmoidf_(float x) { return 1.f / (1.f + __expf(-x)); }

__device__ __forceinline__ void gload16(const void* g, void* l) {
  __builtin_amdgcn_global_load_lds((const __attribute__((address_space(1))) void*)g,
                                   (__attribute__((address_space(3))) void*)l, 16, 0, 0);
}

union FragU { uint2 u2[2]; bf16x8 v; };

// ================= 128x128 bf16 MFMA GEMM (m97 geometry) =================
// BM=128, BN=128, BK=32. 256 threads = 4 waves (2x2), each wave 64x64 (acc 4x4 frags).
// 1D grid with m204 bijective XCD-chunk swizzle. swz=0: decode x-fastest (nx param);
// swz=1: gates grouped decode (12 groups of (rim,n-half), m-outer / n-inner).
// MODE 0: C = A*B (+bias), store f32/bf16. MODE 1: final (+h_new, mask select, 2 outputs).
// MODE 2: gates (dual-source A: k<400 rnn, 400..999 hs2, else zero) + fused LSTM.
template<int MODE>
__global__ __launch_bounds__(256) void gemm128(
    const u16* __restrict__ A, int lda, int strideA,
    const u16* __restrict__ A2, int lda2, int strideA2,
    const u16* __restrict__ Bt, long strideB, int Kpad,
    void* __restrict__ C, int ldc, int strideC,
    const float* __restrict__ bias, int strideBias,
    int N, int nks, int storeBf16, int nx, int swz,
    const u16* __restrict__ zerobuf,
    const float* __restrict__ cs, const float* __restrict__ mask,
    float* __restrict__ c_upd, float* __restrict__ h_upd, u16* __restrict__ hnbf,
    const float* __restrict__ hs_in, float* __restrict__ out_state)
{
  __shared__ __align__(16) u16 As[128 * 32];
  __shared__ __align__(16) u16 Bs[128 * 32];

  // ---- block swizzle (m204 bijective XCD chunk) ----
  const int nwg = gridDim.x;
  const int orig = blockIdx.x;
  const int q = nwg >> 3, r = nwg & 7;
  const int xcd = orig & 7, bidx = orig >> 3;
  const int wgid = (xcd < r ? xcd * (q + 1) : r * (q + 1) + (xcd - r) * q) + bidx;
  int xt, mt, rim;
  if (swz == 0) {
    xt = wgid % nx;
    const int t2 = wgid / nx;
    mt = t2 & 31;
    rim = t2 >> 5;
  } else {
    const int g = wgid / 320;       // (rim, n-half) group; 320 = 32 m-tiles x 10 n-tiles
    const int rem = wgid % 320;
    rim = g >> 1;
    mt = rem / 10;
    xt = (g & 1) * 10 + rem % 10;
    if (xt >= 19) return;
  }
  const int m0 = mt * 128, n0 = xt * 128;

  A += (size_t)rim * strideA;
  if (MODE == 2) A2 += (size_t)rim * strideA2;
  Bt += (size_t)rim * strideB;
  if (bias) bias += (size_t)rim * strideBias;

  const int t = threadIdx.x;
  const int w = t >> 6, lane = t & 63;
  const int lrow = lane & 15, lk = lane >> 4;
  const int wr = w >> 1, wc = w & 1;

  f32x4 acc[4][4] = {};

  // chunk assignment: chunk c -> row c>>2, chunkcol (c&3)^((row>>1)&3). Each thread: c = t, t+256.
  const int rA0 = t >> 2,         cA0 = (t & 3) ^ ((rA0 >> 1) & 3);
  const int rA1 = (t + 256) >> 2, cA1 = (t & 3) ^ ((rA1 >> 1) & 3);

  for (int s = 0; s < nks; ++s) {
    const int k0 = s * 32;
    {
      const int gk0 = k0 + cA0 * 8, gk1 = k0 + cA1 * 8;
      const u16 *p0, *p1;
      if (MODE == 2) {
        p0 = (gk0 < 400)  ? A  + (size_t)(m0 + rA0) * lda  + gk0
           : (gk0 < 1000) ? A2 + (size_t)(m0 + rA0) * lda2 + (gk0 - 400)
                          : zerobuf;
        p1 = (gk1 < 400)  ? A  + (size_t)(m0 + rA1) * lda  + gk1
           : (gk1 < 1000) ? A2 + (size_t)(m0 + rA1) * lda2 + (gk1 - 400)
                          : zerobuf;
      } else {
        p0 = A + (size_t)(m0 + rA0) * lda + gk0;
        p1 = A + (size_t)(m0 + rA1) * lda + gk1;
      }
      gload16(p0, &As[(size_t)t * 8]);
      gload16(p1, &As[(size_t)(t + 256) * 8]);
      gload16(Bt + (size_t)(n0 + rA0) * Kpad + k0 + cA0 * 8, &Bs[(size_t)t * 8]);
      gload16(Bt + (size_t)(n0 + rA1) * Kpad + k0 + cA1 * 8, &Bs[(size_t)(t + 256) * 8]);
    }
    __syncthreads();
    FragU af[4], bfr[4];
#pragma unroll
    for (int mf = 0; mf < 4; ++mf) {
      const int rr = wr * 64 + mf * 16 + lrow;
      const int sw = ((rr >> 1) & 3) << 4;
      const char* base = (const char*)As + rr * 64;
      af[mf].u2[0] = *(const uint2*)(base + ((8 * lk) ^ sw));
      af[mf].u2[1] = *(const uint2*)(base + ((8 * lk + 32) ^ sw));
    }
#pragma unroll
    for (int nf = 0; nf < 4; ++nf) {
      const int rr = wc * 64 + nf * 16 + lrow;
      const int sw = ((rr >> 1) & 3) << 4;
      const char* base = (const char*)Bs + rr * 64;
      bfr[nf].u2[0] = *(const uint2*)(base + ((8 * lk) ^ sw));
      bfr[nf].u2[1] = *(const uint2*)(base + ((8 * lk + 32) ^ sw));
    }
#pragma unroll
    for (int mf = 0; mf < 4; ++mf)
#pragma unroll
      for (int nf = 0; nf < 4; ++nf)
        acc[mf][nf] = __builtin_amdgcn_mfma_f32_16x16x32_bf16(af[mf].v, bfr[nf].v, acc[mf][nf], 0, 0, 0);
    __syncthreads();
  }

  if (MODE == 0) {
    float* Cf = (float*)C + (size_t)rim * strideC;
    u16*   Cu = (u16*)C + (size_t)rim * strideC;
#pragma unroll
    for (int mf = 0; mf < 4; ++mf)
#pragma unroll
      for (int r2 = 0; r2 < 4; ++r2) {
        const int m = m0 + wr * 64 + mf * 16 + 4 * lk + r2;
#pragma unroll
        for (int nf = 0; nf < 4; ++nf) {
          const int col = n0 + wc * 64 + nf * 16 + lrow;
          if (col < N) {
            float v = acc[mf][nf][r2];
            if (bias) v += bias[col];
            const size_t off = (size_t)m * ldc + col;
            if (storeBf16) Cu[off] = f2b(v); else Cf[off] = v;
          }
        }
      }
  } else if (MODE == 1) {
#pragma unroll
    for (int mf = 0; mf < 4; ++mf)
#pragma unroll
      for (int r2 = 0; r2 < 4; ++r2) {
        const int m = m0 + wr * 64 + mf * 16 + 4 * lk + r2;
        const float mk = mask[(size_t)m * 6 + rim];
#pragma unroll
        for (int nf = 0; nf < 4; ++nf) {
          const int col = n0 + wc * 64 + nf * 16 + lrow;
          if (col < 600) {
            const size_t off = (size_t)m * 3600 + rim * 600 + col;
            const float v = (mk != 0.f) ? (acc[mf][nf][r2] + h_upd[off]) : hs_in[off];
            h_upd[off] = v;
            out_state[off] = v;
          }
        }
      }
  } else {  // MODE 2: gates + fused LSTM. 64-col group = {i,f,g,o} x 16 units.
    const int nb = n0 + wc * 64;
    const int u = ((nb >> 6) << 4) + lrow;
    if (u < 600) {
      const float bi  = bias[nb + lrow];
      const float bff = bias[nb + 16 + lrow];
      const float bg  = bias[nb + 32 + lrow];
      const float bo  = bias[nb + 48 + lrow];
#pragma unroll
      for (int mf = 0; mf < 4; ++mf)
#pragma unroll
        for (int r2 = 0; r2 < 4; ++r2) {
          const int m = m0 + wr * 64 + mf * 16 + 4 * lk + r2;
          const float iv = acc[mf][0][r2] + bi;
          const float fv = acc[mf][1][r2] + bff;
          const float gv = acc[mf][2][r2] + bg;
          const float ov = acc[mf][3][r2] + bo;
          const size_t off = (size_t)m * 3600 + rim * 600 + u;
          const float cprev = cs[off];
          const float cv = sigmoidf_(fv) * cprev + sigmoidf_(iv) * tanhf(gv);
          const float hv = sigmoidf_(ov) * tanhf(cv);
          const float mk = mask[(size_t)m * 6 + rim];
          c_upd[off] = (mk != 0.f) ? cv : cprev;
          h_upd[off] = hv;
          hnbf[off]  = f2b(hv);
        }
    }
  }
}

// ================= weight pack: out[n][k] bf16 = in[k][colmap(n)] (LDS transpose) =========
__global__ __launch_bounds__(256) void pack_wt(
    const float* __restrict__ in1, long s1,
    const float* __restrict__ in2, long s2,
    int K1, int Ktot, int ldin, int Nreal,
    u16* __restrict__ out, long so, int Kpad, int gateperm)
{
  __shared__ float tile[64][65];
  const int rim = blockIdx.z;
  const float* i1 = in1 + (size_t)rim * s1;
  const float* i2 = in2 ? in2 + (size_t)rim * s2 : nullptr;
  u16* o = out + (size_t)rim * so;
  const int n0 = blockIdx.x * 64, k0 = blockIdx.y * 64;
  const int lane = threadIdx.x & 63, qq = threadIdx.x >> 6;
  const int n = n0 + lane;
  int col;
  if (gateperm) {
    const int g = (n >> 4) & 3, u = ((n >> 6) << 4) + (n & 15);
    col = (u < 600) ? g * 600 + u : -1;
  } else {
    col = (n < Nreal) ? n : -1;
  }
#pragma unroll
  for (int i = 0; i < 16; ++i) {
    const int kk = qq + 4 * i;
    const int k = k0 + kk;
    float v = 0.f;
    if (col >= 0) {
      if (k < K1) v = i1[(size_t)k * ldin + col];
      else if (k < Ktot) v = i2[(size_t)(k - K1) * ldin + col];
    }
    tile[kk][lane] = v;
  }
  __syncthreads();
#pragma unroll
  for (int i = 0; i < 16; ++i) {
    const int nn = qq + 4 * i;
    const int k = k0 + lane;
    if (k < Kpad) o[(size_t)(n0 + nn) * Kpad + k] = f2b(tile[lane][nn]);
  }
}

// combined [Wk | head-avg(Wv)] -> [768][512]
__global__ void pack_kvw(const float* __restrict__ Wk, const float* __restrict__ Wv,
                         u16* __restrict__ out) {
  const int i = blockIdx.x * 256 + threadIdx.x;
  if (i >= 768 * 512) return;
  const int n = i >> 9, k = i & 511;
  float v = 0.f;
  if (n < 256) v = Wk[(size_t)k * 256 + n];
  else if (n < 656) {
    const float* p = Wv + (size_t)k * 1600 + (n - 256);
    v = 0.25f * (p[0] + p[400] + p[800] + p[1200]);
  }
  out[i] = f2b(v);
}

// combined [Wkc | Wqc | Wvc] -> [6][768][608]
__global__ void pack_comw(const float* __restrict__ Wkc, const float* __restrict__ Wqc,
                          const float* __restrict__ Wvc, u16* __restrict__ out) {
  const long long i = (long long)blockIdx.x * 256 + threadIdx.x;
  if (i >= 6ll * 768 * 608) return;
  const int rim = (int)(i / (768 * 608));
  const int rem = (int)(i % (768 * 608));
  const int n = rem / 608, k = rem % 608;
  float v = 0.f;
  if (k < 600) {
    if (n < 128)      v = Wkc[(size_t)rim * 600 * 128 + (size_t)k * 128 + n];
    else if (n < 256) v = Wqc[(size_t)rim * 600 * 128 + (size_t)k * 128 + (n - 128)];
    else if (n < 656) v = Wvc[(size_t)rim * 600 * 400 + (size_t)k * 400 + (n - 256)];
  }
  out[i] = f2b(v);
}

__global__ void pack_misc(const float* __restrict__ lstm_b, const float* __restrict__ bk,
                          const float* __restrict__ bv,
                          float* __restrict__ bp, float* __restrict__ bkv, u16* __restrict__ zerobuf) {
  const int t = blockIdx.x * 256 + threadIdx.x;
  if (t < 6 * 2432) {
    const int rim = t / 2432, p = t % 2432;
    const int g = (p >> 4) & 3, u = ((p >> 6) << 4) + (p & 15);
    bp[t] = (u < 600) ? lstm_b[(size_t)rim * 2400 + g * 600 + u] : 0.f;
  }
  if (t < 768) {
    float v = 0.f;
    if (t < 256) v = bk[t];
    else if (t < 656) { const int j = t - 256; v = 0.25f * (bv[j] + bv[j + 400] + bv[j + 800] + bv[j + 1200]); }
    bkv[t] = v;
  }
  if (t < 128) zerobuf[t] = 0;
}

__global__ void pack_x(const float* __restrict__ inputs, u16* __restrict__ xbf) {
  const int idx = blockIdx.x * 256 + threadIdx.x;
  if (idx < 4096 * 512) {
    const int b = idx >> 9, c = idx & 511;
    xbf[idx] = f2b(inputs[(size_t)b * 518 + c]);
  }
}

__global__ void pack_hs2(const float* __restrict__ hs, u16* __restrict__ out) {
  const long long idx = (long long)blockIdx.x * 256 + threadIdx.x;
  const long long total = 4096ll * 3600 + 64;
  if (idx < total) out[idx] = f2b(idx < 4096ll * 3600 ? hs[idx] : 0.f);
}

// ============ scores + softmax + top-k mask + rnn_in ============
__global__ __launch_bounds__(256) void score_kernel(
    const float* __restrict__ inputs, const u16* __restrict__ qlayb,
    const u16* __restrict__ kvb, const float* __restrict__ bk,
    const float* __restrict__ bkv,
    float* __restrict__ maskout, u16* __restrict__ rnnin)
{
  const int b = blockIdx.x;
  const int t = threadIdx.x;
  __shared__ float red[4][12];
  __shared__ float sprob[12];
  __shared__ float smask[6];

  const float k0v = b2f(kvb[(size_t)b * 768 + t]);
  const float bkv_ = bk[t];
  float part[12];
#pragma unroll
  for (int n = 0; n < 6; ++n) {
    const float q = b2f(qlayb[(size_t)b * 1536 + n * 256 + t]);
    part[2 * n]     = q * k0v;
    part[2 * n + 1] = q * bkv_;
  }
#pragma unroll
  for (int off = 32; off > 0; off >>= 1)
#pragma unroll
    for (int i = 0; i < 12; ++i)
      part[i] += __shfl_down(part[i], off);
  const int wave = t >> 6, lane = t & 63;
  if (lane == 0)
#pragma unroll
    for (int i = 0; i < 12; ++i) red[wave][i] = part[i];
  __syncthreads();
  if (t < 12) red[0][t] = (red[0][t] + red[1][t] + red[2][t] + red[3][t]) * (1.0f / 32.0f);
  __syncthreads();
  if (t < 6) {
    const float s0 = red[0][2 * t], s1 = red[0][2 * t + 1];
    const float mx = fmaxf(s0, s1);
    const float e0 = __expf(s0 - mx), e1 = __expf(s1 - mx);
    const float inv = 1.f / (e0 + e1);
    sprob[2 * t] = e0 * inv;
    sprob[2 * t + 1] = e1 * inv;
    const float* rd = inputs + (size_t)b * 518 + 512;
    const float mine = rd[t];
    int rank = 0;
#pragma unroll
    for (int j = 0; j < 6; ++j) {
      const float o = rd[j];
      rank += (o > mine) || (o == mine && j < t);
    }
    const float mk = (rank < 4) ? 1.f : 0.f;
    smask[t] = mk;
    maskout[(size_t)b * 6 + t] = mk;
  }
  __syncthreads();
  for (int idx = t; idx < 2400; idx += 256) {
    const int n = idx / 400, v = idx % 400;
    const float val = (sprob[2 * n] * b2f(kvb[(size_t)b * 768 + 256 + v]) + sprob[2 * n + 1] * bkv[256 + v]) * smask[n];
    rnnin[(size_t)b * 2400 + idx] = f2b(val);
  }
}

// ============ comm attention ============
__global__ __launch_bounds__(256) void comm_kernel(
    const u16* __restrict__ cqv, u16* __restrict__ ctx)
{
  const int b = blockIdx.x, t = threadIdx.x;
  __shared__ float skc[768], sqc[768], svc[2400];
  __shared__ float spc[4][6][6];
  for (int i = t; i < 4608; i += 256) {
    const int m = i / 768, c = i % 768;
    const float v = b2f(cqv[(size_t)b * 4608 + i]);
    if (c < 128) skc[m * 128 + c] = v;
    else if (c < 256) sqc[m * 128 + (c - 128)] = v;
    else if (c < 656) svc[m * 400 + (c - 256)] = v;
  }
  __syncthreads();
  if (t < 144) {
    const int h = t / 36, n = (t % 36) / 6, m = t % 6;
    float s = 0.f;
#pragma unroll
    for (int d = 0; d < 32; ++d) s += sqc[n * 128 + h * 32 + d] * skc[m * 128 + h * 32 + d];
    spc[h][n][m] = s * 0.17677669529663687f;
  }
  __syncthreads();
  if (t < 24) {
    const int h = t / 6, n = t % 6;
    float mx = -3.0e38f;
#pragma unroll
    for (int m = 0; m < 6; ++m) mx = fmaxf(mx, spc[h][n][m]);
    float e[6], sum = 0.f;
#pragma unroll
    for (int m = 0; m < 6; ++m) { e[m] = __expf(spc[h][n][m] - mx); sum += e[m]; }
    const float inv = 1.f / sum;
#pragma unroll
    for (int m = 0; m < 6; ++m) spc[h][n][m] = e[m] * inv;
  }
  __syncthreads();
  for (int idx = t; idx < 2400; idx += 256) {
    const int n = idx / 400, rr = idx % 400, h = rr / 100, v = rr % 100;
    float s = 0.f;
#pragma unroll
    for (int m = 0; m < 6; ++m) s += spc[h][n][m] * svc[m * 400 + h * 100 + v];
    ctx[(size_t)b * 2400 + idx] = f2b(s);
  }
}

// ================= launch =================
extern "C" void kernel_launch(void* const* d_in, const int* in_sizes, int n_in,
                              void* d_out, int out_size, void* d_ws, size_t ws_size,
                              hipStream_t stream) {
  const float* inputs = (const float*)d_in[0];
  const float* hs     = (const float*)d_in[1];
  const float* cs     = (const float*)d_in[2];
  const float* Wk     = (const float*)d_in[3];
  const float* bk     = (const float*)d_in[4];
  const float* Wv     = (const float*)d_in[5];
  const float* bv     = (const float*)d_in[6];
  const float* Wq     = (const float*)d_in[7];
  const float* lstm_k = (const float*)d_in[8];
  const float* lstm_r = (const float*)d_in[9];
  const float* lstm_b = (const float*)d_in[10];
  const float* Wkc    = (const float*)d_in[11];
  const float* Wvc    = (const float*)d_in[12];
  const float* Wqc    = (const float*)d_in[13];
  const float* Wout   = (const float*)d_in[14];

  float* out = (float*)d_out;
  float* out_state = out;
  float* h_upd = out + kOS;
  float* c_upd = out + 2 * kOS;
  u16*   hnbf  = (u16*)d_out;     // scratch alias in out_state slot (dead until final GEMM)

  char* wsb = (char*)d_ws;
  u16* WkvT  = (u16*)(wsb + oWkvT);
  u16* WqT   = (u16*)(wsb + oWqT);
  u16* WcomT = (u16*)(wsb + oWcomT);
  u16* WoutT = (u16*)(wsb + oWoutT);
  u16* LstmT = (u16*)(wsb + oLstmT);
  float* bp    = (float*)(wsb + oBp);
  float* bkv   = (float*)(wsb + oBkv);
  u16*   zerob = (u16*)(wsb + oZero);
  float* maskf = (float*)(wsb + oMask);
  u16* hs2   = (u16*)(wsb + oHs2);
  u16* rnn   = (u16*)(wsb + oRnn);
  u16* kvb   = (u16*)(wsb + oKV);
  u16* xbf   = (u16*)(wsb + oXbf);
  u16* qlayb = (u16*)(wsb + oQlay);
  u16* cqvb  = (u16*)(wsb + oCqv);
  u16* ctxb  = (u16*)(wsb + oCtx);

  dim3 B256(256);

  // ---- packs ----
  pack_misc<<<57, B256, 0, stream>>>(lstm_b, bk, bv, bp, bkv, zerob);
  pack_kvw<<<1536, B256, 0, stream>>>(Wk, Wv, WkvT);
  pack_comw<<<10944, B256, 0, stream>>>(Wkc, Wqc, Wvc, WcomT);
  pack_wt<<<dim3(4, 10, 6), B256, 0, stream>>>(Wq, 600ll*256, nullptr, 0, 600, 600, 256, 256, WqT, 256ll*608, 608, 0);
  pack_wt<<<dim3(10, 7, 6), B256, 0, stream>>>(Wout, 400ll*600, nullptr, 0, 400, 400, 600, 600, WoutT, 640ll*416, 416, 0);
  pack_wt<<<dim3(38, 16, 6), B256, 0, stream>>>(lstm_k, 400ll*2400, lstm_r, 600ll*2400, 400, 1000, 2400, 2400, LstmT, 2432ll*1024, 1024, 1);
  pack_x<<<8192, B256, 0, stream>>>(inputs, xbf);
  pack_hs2<<<57601, B256, 0, stream>>>(hs, hs2);

  // ---- kv = [x@Wk+bk | x@Wvavg+bvavg]  (N=656, K=512) ----
  gemm128<0><<<dim3(6*32), B256, 0, stream>>>(xbf, 512, 0, nullptr, 0, 0, WkvT, 0, 512,
      kvb, 768, 0, bkv, 0, 656, 16, 1, 6, 0, zerob,
      nullptr, nullptr, nullptr, nullptr, nullptr, nullptr, nullptr);
  // ---- qlay (N=256/rim, K=608) — overlays xbf, runs after kv ----
  gemm128<0><<<dim3(2*32*6), B256, 0, stream>>>(hs2, 3600, 600, nullptr, 0, 0, WqT, 256*608, 608,
      qlayb, 1536, 256, nullptr, 0, 256, 19, 1, 2, 0, zerob,
      nullptr, nullptr, nullptr, nullptr, nullptr, nullptr, nullptr);

  score_kernel<<<4096, B256, 0, stream>>>(inputs, qlayb, kvb, bk, bkv, maskf, rnn);

  // ---- gates (N=2432, K=1024) + fused LSTM; grouped XCD swizzle ----
  gemm128<2><<<dim3(3840), B256, 0, stream>>>(rnn, 2400, 400, hs2, 3600, 600, LstmT, 2432l*1024, 1024,
      nullptr, 0, 0, bp, 2432, 2432, 32, 0, 10, 1, zerob,
      cs, maskf, c_upd, h_upd, hnbf, nullptr, nullptr);

  // ---- comm projections fused: [kc|qc|vc] (N=656/rim, K=608) ----
  gemm128<0><<<dim3(6*32*6), B256, 0, stream>>>(hnbf, 3600, 600, nullptr, 0, 0, WcomT, 768l*608, 608,
      cqvb, 4608, 768, nullptr, 0, 656, 19, 1, 6, 0, zerob,
      nullptr, nullptr, nullptr, nullptr, nullptr, nullptr, nullptr);

  comm_kernel<<<4096, B256, 0, stream>>>(cqvb, ctxb);

  // ---- final: h_comm = ctx@Wout + h_new; masked select (N=640 pad, K=416) ----
  gemm128<1><<<dim3(5*32*6), B256, 0, stream>>>(ctxb, 2400, 400, nullptr, 0, 0, WoutT, 640l*416, 416,
      nullptr, 0, 0, nullptr, 0, 600, 13, 0, 5, 0, zerob,
      nullptr, maskf, nullptr, h_upd, nullptr, hs, out_state);
}